// Round 2
// 626.653 us; speedup vs baseline: 1.1368x; 1.1368x over previous
//
#include <hip/hip_runtime.h>
#include <math.h>

#define BATCH 8
#define CD 64      // channels (K of the score GEMM)
#define ND 4096    // spatial positions
#define MR 64      // attn rows per block -> 512 blocks -> 2 blocks/CU

typedef short bf16x8 __attribute__((ext_vector_type(8)));
typedef float f32x4 __attribute__((ext_vector_type(4)));

static __device__ __forceinline__ unsigned short f2bf(float f) {
    unsigned int u = __float_as_uint(f);
    u += 0x7fff + ((u >> 16) & 1);   // RNE
    return (unsigned short)(u >> 16);
}
static __device__ __forceinline__ float bf2f(unsigned short h) {
    return __uint_as_float(((unsigned int)h) << 16);
}

// ---------------------------------------------------------------------------
// convert_kernel: x[b][c][n] fp32 ->
//   xt_hi/xt_lo [b][n][c] bf16 (split pair, for QK^T A/B fragments)
//   xcm_hi      [b][c][n] bf16 (for PV B fragments)
//   norms       [b][n]    fp32 ||x_n||^2  (softmax shift: the diagonal of S)
// ---------------------------------------------------------------------------
__global__ __launch_bounds__(256) void convert_kernel(const float* __restrict__ x,
        unsigned short* __restrict__ xt_hi, unsigned short* __restrict__ xt_lo,
        unsigned short* __restrict__ xcm_hi, float* __restrict__ norms) {
    __shared__ unsigned short Thi[64][68];
    __shared__ unsigned short Tlo[64][68];
    const int b = blockIdx.y, n0 = blockIdx.x * 64, t = threadIdx.x;
    const float* xb = x + (size_t)b * CD * ND;

    for (int r = 0; r < 4; ++r) {
        int f4 = t + r * 256;            // 0..1023 float4 index in 64x64 tile
        int c  = f4 >> 4;
        int nc = (f4 & 15) * 4;
        float4 v = *(const float4*)&xb[(size_t)c * ND + n0 + nc];
        float vv[4] = {v.x, v.y, v.z, v.w};
        unsigned long long packed = 0;
        for (int j = 0; j < 4; ++j) {
            unsigned short hi = f2bf(vv[j]);
            unsigned short lo = f2bf(vv[j] - bf2f(hi));
            Thi[c][nc + j] = hi;
            Tlo[c][nc + j] = lo;
            packed |= ((unsigned long long)hi) << (16 * j);
        }
        *(unsigned long long*)&xcm_hi[((size_t)b * CD + c) * ND + n0 + nc] = packed;
    }
    __syncthreads();

    // transposed write: thread t handles n = t>>2, c0 = (t&3)*16
    const int n = t >> 2, c0 = (t & 3) * 16;
    unsigned short hb[16], lb[16];
    float nrm = 0.f;
    #pragma unroll
    for (int j = 0; j < 16; ++j) {
        hb[j] = Thi[c0 + j][n];
        lb[j] = Tlo[c0 + j][n];
        float xv = bf2f(hb[j]) + bf2f(lb[j]);
        nrm = fmaf(xv, xv, nrm);
    }
    size_t base = ((size_t)b * ND + n0 + n) * CD + c0;
    *(uint4*)&xt_hi[base]     = *(uint4*)&hb[0];
    *(uint4*)&xt_hi[base + 8] = *(uint4*)&hb[8];
    *(uint4*)&xt_lo[base]     = *(uint4*)&lb[0];
    *(uint4*)&xt_lo[base + 8] = *(uint4*)&lb[8];

    // per-n squared norm: 4 threads (t&3) hold 16-channel partials each
    nrm += __shfl_xor(nrm, 1);
    nrm += __shfl_xor(nrm, 2);
    if ((t & 3) == 0) norms[(size_t)b * ND + n0 + n] = nrm;
}

// ---------------------------------------------------------------------------
// Fused attention: 256 threads (4 waves), each block owns 64 attn rows
// (wave w owns rows w*16..w*16+15). 512 blocks -> 2 blocks/CU.
// Softmax shift M_n = ||x_n||^2 (diagonal of S): s-M <= maxnorm^2/4 (~34 for
// N(0,1) data) so exp never overflows; diag term is exp(0)=1 so the row sum
// never underflows. Normalization makes the result identical to max-shift.
// Pass 1: S = X^T X (split-bf16 MFMA), accumulate sum of exp(s-M) only.
// Pass 2: recompute S, p = exp(s-M)*inv -> attn (nontemporal) + Ppv -> PV.
// B/X tiles double-buffered in LDS with register prefetch (1 barrier/iter).
// MFMA layouts (m89/m101/m120-verified):
//   A-frag: A[row = lane&15][k = (lane>>4)*8 + j]
//   B-frag: B[k = (lane>>4)*8 + j][col = lane&15]
//   C/D   : D[row = (lane>>4)*4 + reg][col = lane&15]
// ---------------------------------------------------------------------------
__global__ __launch_bounds__(256, 2) void attn_kernel(
        const unsigned short* __restrict__ xt_hi,
        const unsigned short* __restrict__ xt_lo,
        const unsigned short* __restrict__ xcm_hi,
        const float* __restrict__ norms,
        float* __restrict__ y, float* __restrict__ attn) {
    __shared__ unsigned short Bhi[2][64][72];   // 18432 B
    __shared__ unsigned short Blo[2][64][72];   // 18432 B
    __shared__ unsigned short Xpv[2][64][72];   // 18432 B
    __shared__ unsigned short Ppv[64][72];      //  9216 B -> 64512 total

    const int t  = threadIdx.x;
    const int w  = t >> 6;      // wave 0..3, owns rows w*16..w*16+15
    const int l  = t & 63;
    const int q  = l >> 4;      // quad
    const int lc = l & 15;

    // XCD-chunked swizzle: consecutive hw blocks round-robin XCDs; remap so
    // XCD k processes exactly batch k (per-XCD working set 1.5 MB, L2-fits).
    const int lin = blockIdx.x + gridDim.x * blockIdx.y;   // 0..511
    const int swz = (lin & 7) * 64 + (lin >> 3);           // bijective
    const int b  = swz >> 6;
    const int n0 = (swz & 63) * MR;

    const unsigned short* xthi_b = xt_hi + (size_t)b * ND * CD;
    const unsigned short* xtlo_b = xt_lo + (size_t)b * ND * CD;
    const unsigned short* xcm_b  = xcm_hi + (size_t)b * CD * ND;
    const float* norms_b = norms + (size_t)b * ND;
    float* attn_b = attn + (size_t)b * ND * ND;

    // A fragments live in registers (invariant over the whole kernel):
    // lane's A row = n0 + w*16 + lc, k-chunks at ks*32 + q*8
    const size_t arow = (size_t)(n0 + w * 16 + lc) * CD;
    const bf16x8 ah0 = *(const bf16x8*)(const void*)&xthi_b[arow + q * 8];
    const bf16x8 ah1 = *(const bf16x8*)(const void*)&xthi_b[arow + 32 + q * 8];
    const bf16x8 al0 = *(const bf16x8*)(const void*)&xtlo_b[arow + q * 8];
    const bf16x8 al1 = *(const bf16x8*)(const void*)&xtlo_b[arow + 32 + q * 8];

    // per-lane softmax shifts for its 4 C-rows (q*4+i)
    const float4 Mv = *(const float4*)&norms_b[n0 + w * 16 + q * 4];
    const float M[4] = {Mv.x, Mv.y, Mv.z, Mv.w};

    // staging mapping: thread t loads 32 contiguous B of row t>>2 at col (t&3)*16
    const int srow = t >> 2;
    const int skk  = (t & 3) * 16;

    uint4 ph0, ph1, pl0, pl1, px0, px1;
    auto loadB = [&](int m0) {
        const size_t rb = (size_t)(m0 + srow) * CD + skk;
        ph0 = *(const uint4*)&xthi_b[rb];
        ph1 = *(const uint4*)&xthi_b[rb + 8];
        pl0 = *(const uint4*)&xtlo_b[rb];
        pl1 = *(const uint4*)&xtlo_b[rb + 8];
    };
    auto writeB = [&](int buf) {
        *(uint4*)&Bhi[buf][srow][skk]     = ph0;
        *(uint4*)&Bhi[buf][srow][skk + 8] = ph1;
        *(uint4*)&Blo[buf][srow][skk]     = pl0;
        *(uint4*)&Blo[buf][srow][skk + 8] = pl1;
    };
    auto loadX = [&](int m0) {
        const size_t rx = (size_t)srow * ND + m0 + skk;
        px0 = *(const uint4*)&xcm_b[rx];
        px1 = *(const uint4*)&xcm_b[rx + 8];
    };
    auto writeX = [&](int buf) {
        *(uint4*)&Xpv[buf][srow][skk]     = px0;
        *(uint4*)&Xpv[buf][srow][skk + 8] = px1;
    };

    // split-bf16 S-tile: 16 rows (this wave) x 16 cols (ct) x K=64
    auto computeS = [&](int cb, int ct) -> f32x4 {
        const unsigned short* bhp = &Bhi[cb][ct * 16 + lc][q * 8];
        const unsigned short* blp = &Blo[cb][ct * 16 + lc][q * 8];
        bf16x8 bh0 = *(const bf16x8*)(const void*)bhp;
        bf16x8 bh1 = *(const bf16x8*)(const void*)(bhp + 32);
        bf16x8 bl0 = *(const bf16x8*)(const void*)blp;
        bf16x8 bl1 = *(const bf16x8*)(const void*)(blp + 32);
        f32x4 a0 = {0.f, 0.f, 0.f, 0.f}, a1 = {0.f, 0.f, 0.f, 0.f};
        a0 = __builtin_amdgcn_mfma_f32_16x16x32_bf16(ah0, bh0, a0, 0, 0, 0);
        a1 = __builtin_amdgcn_mfma_f32_16x16x32_bf16(ah1, bh1, a1, 0, 0, 0);
        a0 = __builtin_amdgcn_mfma_f32_16x16x32_bf16(ah0, bl0, a0, 0, 0, 0);
        a1 = __builtin_amdgcn_mfma_f32_16x16x32_bf16(ah1, bl1, a1, 0, 0, 0);
        a0 = __builtin_amdgcn_mfma_f32_16x16x32_bf16(al0, bh0, a0, 0, 0, 0);
        a1 = __builtin_amdgcn_mfma_f32_16x16x32_bf16(al1, bh1, a1, 0, 0, 0);
        return a0 + a1;
    };

    // ------------------------- pass 1: row sums -------------------------
    float ssum[4] = {0.f, 0.f, 0.f, 0.f};
    loadB(0);
    writeB(0);
    __syncthreads();
    int cur = 0;
    for (int it = 0; it < ND / 64; ++it) {
        loadB(((it + 1) & 63) * 64);   // prefetch next tile into regs
        #pragma unroll
        for (int ct = 0; ct < 4; ++ct) {
            f32x4 s = computeS(cur, ct);
            #pragma unroll
            for (int i = 0; i < 4; ++i) ssum[i] += __expf(s[i] - M[i]);
        }
        writeB(cur ^ 1);
        cur ^= 1;
        __syncthreads();
    }

    // reduce sums across the 16 lanes (same quad) holding each row
    float inv[4];
    #pragma unroll
    for (int i = 0; i < 4; ++i) {
        float s = ssum[i];
        s += __shfl_xor(s, 1);
        s += __shfl_xor(s, 2);
        s += __shfl_xor(s, 4);
        s += __shfl_xor(s, 8);
        inv[i] = 1.0f / s;
    }

    // ------------------- pass 2: write attn, accumulate y -------------------
    f32x4 pvacc[4];
    #pragma unroll
    for (int ct = 0; ct < 4; ++ct) { f32x4 z = {0.f, 0.f, 0.f, 0.f}; pvacc[ct] = z; }

    // B buffers: buf0 already holds tile 0 (written during pass-1 epilogue).
    loadX(0);
    writeX(0);
    __syncthreads();
    cur = 0;
    for (int it = 0; it < ND / 64; ++it) {
        const int m0 = it * 64;
        const int mn = ((it + 1) & 63) * 64;
        loadB(mn);
        loadX(mn);

        #pragma unroll
        for (int ct = 0; ct < 4; ++ct) {
            f32x4 s = computeS(cur, ct);
            #pragma unroll
            for (int i = 0; i < 4; ++i) {
                float p = __expf(s[i] - M[i]) * inv[i];
                __builtin_nontemporal_store(p,
                    &attn_b[(size_t)(n0 + w * 16 + q * 4 + i) * ND + m0 + ct * 16 + lc]);
                Ppv[w * 16 + q * 4 + i][ct * 16 + lc] = f2bf(p);
            }
        }
        __asm__ volatile("s_waitcnt lgkmcnt(0)" ::: "memory");  // wave-local P visibility

        // PV: y-tile += P (A-frag) * Xpv (B-frag)
        #pragma unroll
        for (int ks = 0; ks < 2; ++ks) {
            bf16x8 pa = *(const bf16x8*)(const void*)&Ppv[w * 16 + lc][ks * 32 + q * 8];
            #pragma unroll
            for (int ct = 0; ct < 4; ++ct) {
                bf16x8 xv = *(const bf16x8*)(const void*)&Xpv[cur][ct * 16 + lc][ks * 32 + q * 8];
                pvacc[ct] = __builtin_amdgcn_mfma_f32_16x16x32_bf16(pa, xv, pvacc[ct], 0, 0, 0);
            }
        }

        writeB(cur ^ 1);
        writeX(cur ^ 1);
        cur ^= 1;
        __syncthreads();
    }

    // y[b][c][n], 4 consecutive n per store
    #pragma unroll
    for (int ct = 0; ct < 4; ++ct) {
        int c = ct * 16 + lc;
        int n = n0 + w * 16 + q * 4;
        float4 v = make_float4(pvacc[ct][0], pvacc[ct][1], pvacc[ct][2], pvacc[ct][3]);
        *(float4*)&y[((size_t)b * CD + c) * ND + n] = v;
    }
}

extern "C" void kernel_launch(void* const* d_in, const int* in_sizes, int n_in,
                              void* d_out, int out_size, void* d_ws, size_t ws_size,
                              hipStream_t stream) {
    const float* x = (const float*)d_in[0];
    float* y    = (float*)d_out;
    float* attn = (float*)d_out + (size_t)BATCH * CD * ND;

    // ws: xt_hi | xt_lo | xcm_hi (each 4 MB) | norms (128 KB)
    unsigned short* xt_hi  = (unsigned short*)d_ws;
    unsigned short* xt_lo  = xt_hi + (size_t)BATCH * ND * CD;
    unsigned short* xcm_hi = xt_lo + (size_t)BATCH * ND * CD;
    float* norms = (float*)(xcm_hi + (size_t)BATCH * CD * ND);

    convert_kernel<<<dim3(ND / 64, BATCH), 256, 0, stream>>>(x, xt_hi, xt_lo, xcm_hi, norms);
    attn_kernel<<<dim3(ND / MR, BATCH), 256, 0, stream>>>(xt_hi, xt_lo, xcm_hi, norms, y, attn);
}